// Round 2
// baseline (804.029 us; speedup 1.0000x reference)
//
#include <hip/hip_runtime.h>
#include <hip/hip_bf16.h>
#include <stdint.h>

typedef __bf16 bf16x8 __attribute__((ext_vector_type(8)));
typedef float  f32x4  __attribute__((ext_vector_type(4)));

__device__ __forceinline__ void gload_lds16(const void* g, void* l) {
  __builtin_amdgcn_global_load_lds(
      (const __attribute__((address_space(1))) void*)g,
      (__attribute__((address_space(3))) void*)l, 16, 0, 0);
}

// Stage one 128x64 bf16 half-tile (K-major src, row stride ldk) into LDS in
// granule-transposed layout: LDS granule g (16B) holds (seg = g>>7, row = g&127),
// i.e. element offset (seg*128 + row)*8. Linear LDS dest (global_load_lds
// requirement), per-lane permuted global source.
__device__ __forceinline__ void stage_half(const __bf16* __restrict__ src, int ldk,
                                           __bf16* lds, int t, int w) {
#pragma unroll
  for (int i = 0; i < 2; ++i) {
    const int g = i * 512 + t;
    const int seg = g >> 7, row = g & 127;
    gload_lds16(src + (size_t)row * ldk + seg * 8,
                lds + (size_t)(i * 512 + w * 64) * 8);
  }
}

// ---------------- RMSNorm: fp32 row (H=2048) -> bf16 row ----------------
__global__ __launch_bounds__(256) void rmsnorm_kernel(
    const float* __restrict__ x, const float* __restrict__ w,
    __bf16* __restrict__ out) {
  constexpr int H = 2048;
  const int row = blockIdx.x;
  const int t = threadIdx.x;
  const float4* xr = (const float4*)(x + (size_t)row * H);
  float4 a = xr[t * 2 + 0];
  float4 b = xr[t * 2 + 1];
  float ss = a.x*a.x + a.y*a.y + a.z*a.z + a.w*a.w
           + b.x*b.x + b.y*b.y + b.z*b.z + b.w*b.w;
#pragma unroll
  for (int o = 32; o > 0; o >>= 1) ss += __shfl_xor(ss, o);
  __shared__ float red[4];
  if ((t & 63) == 0) red[t >> 6] = ss;
  __syncthreads();
  float tot = red[0] + red[1] + red[2] + red[3];
  float r = rsqrtf(tot * (1.0f / H) + 1e-6f);
  const float4* wr4 = (const float4*)w;
  float4 wa = wr4[t * 2 + 0];
  float4 wb = wr4[t * 2 + 1];
  bf16x8 ov;
  ov[0] = (__bf16)(a.x * wa.x * r);
  ov[1] = (__bf16)(a.y * wa.y * r);
  ov[2] = (__bf16)(a.z * wa.z * r);
  ov[3] = (__bf16)(a.w * wa.w * r);
  ov[4] = (__bf16)(b.x * wb.x * r);
  ov[5] = (__bf16)(b.y * wb.y * r);
  ov[6] = (__bf16)(b.z * wb.z * r);
  ov[7] = (__bf16)(b.w * wb.w * r);
  *(bf16x8*)(out + (size_t)row * H + (size_t)t * 8) = ov;
}

// ---------------- AWQ dequant -> transposed bf16 weight (N x K) ----------------
__global__ __launch_bounds__(256) void dequant_t_kernel(
    const int* __restrict__ qw, const int* __restrict__ qz,
    const float* __restrict__ sc, __bf16* __restrict__ wt,
    int K, int Cp, int Nfull) {
  const int t = threadIdx.x;
  const int k = blockIdx.x * 64 + (t & 63);
  const int c0 = blockIdx.y * 64 + (t >> 6) * 16;
  const int g = k >> 7;  // GROUP_SIZE = 128
  const uint32_t* qwr = (const uint32_t*)qw + (size_t)k * Cp + c0;
  const uint32_t* qzr = (const uint32_t*)qz + (size_t)g * Cp + c0;
  const float* scr = sc + (size_t)g * Nfull + (size_t)c0 * 8;

  uint32_t u[16], z[16];
  *(int4*)(&u[0])  = *(const int4*)(qwr + 0);
  *(int4*)(&u[4])  = *(const int4*)(qwr + 4);
  *(int4*)(&u[8])  = *(const int4*)(qwr + 8);
  *(int4*)(&u[12]) = *(const int4*)(qwr + 12);
  *(int4*)(&z[0])  = *(const int4*)(qzr + 0);
  *(int4*)(&z[4])  = *(const int4*)(qzr + 4);
  *(int4*)(&z[8])  = *(const int4*)(qzr + 8);
  *(int4*)(&z[12]) = *(const int4*)(qzr + 12);

#pragma unroll
  for (int i = 0; i < 16; i++) {
    const uint32_t uu = u[i], zz = z[i];
#pragma unroll
    for (int s = 0; s < 8; s++) {
      const int sh = ((s >> 1) * 4) + ((s & 1) ? 16 : 0);  // {0,16,4,20,8,24,12,28}
      float wv = ((float)((uu >> sh) & 15u) - (float)((zz >> sh) & 15u)) * scr[i * 8 + s];
      wt[((size_t)(c0 + i) * 8 + s) * (size_t)K + k] = (__bf16)wv;
    }
  }
}

// ---------------- 8-phase 256xBN bf16 GEMM (B transposed: [N][K]) ----------------
// BN in {256,128}. 512 threads, 8 waves. BK=64, 2 LDS dbufs.
// EPI 0: C (bf16) = A @ B^T      EPI 1: C (f32) = addend + A @ B^T
template <int BN, int EPI>
__global__ __launch_bounds__(512, 2) void gemm8p_kernel(
    const __bf16* __restrict__ A, const __bf16* __restrict__ Bt,
    void* __restrict__ Cv, const float* __restrict__ addend,
    int M, int N, int K) {
  constexpr int BH = BN / 128;             // B half-tiles per K-tile (2 or 1)
  constexpr int WM = (BN == 256) ? 2 : 4;  // waves along M
  constexpr int WR = 256 / WM;             // rows per wave (128 or 64)
  constexpr int MI = WR / 16;              // 8 or 4 row-fragments per wave
  constexpr int MIP = MI / 4;              // mi per phase (2 or 1)

  __shared__ __bf16 As[2][2][8192];        // [dbuf][half][seg*128+row | *8]
  __shared__ __bf16 Bs[2][BH][8192];

  const int t = threadIdx.x;
  const int w = t >> 6, l = t & 63;
  const int lm = l & 15, kb = l >> 4;
  const int wm = (BN == 256) ? (w >> 2) : (w >> 1);
  const int wn = (BN == 256) ? (w & 3) : (w & 1);

  // XCD-aware bijective swizzle (all launches have nwg % 8 == 0)
  const int nwg = gridDim.x;
  const int bid0 = blockIdx.x;
  const int swz = (bid0 & 7) * (nwg >> 3) + (bid0 >> 3);
  const int nbx = N / BN;
  const int bn0 = (swz % nbx) * BN;
  const int bm0 = (swz / nbx) * 256;

  const int ah  = (wm * WR) >> 7;          // A-half this wave reads
  const int ar0 = (wm * WR) & 127;         // base row within half
  const int bh  = (wn * 64) >> 7;          // B-half this wave reads
  const int bc0 = (wn * 64) & 127;         // base col within half

  const __bf16* Ab = A + (size_t)bm0 * K;
  const __bf16* Bb = Bt + (size_t)bn0 * K;
  const int NT = K >> 6;

  // Prologue: stage A(0) both halves, B(0), B(1).
  stage_half(Ab, K, &As[0][0][0], t, w);
  stage_half(Ab + (size_t)128 * K, K, &As[0][1][0], t, w);
#pragma unroll
  for (int h = 0; h < BH; ++h)
    stage_half(Bb + (size_t)(h * 128) * K, K, &Bs[0][h][0], t, w);
#pragma unroll
  for (int h = 0; h < BH; ++h)
    stage_half(Bb + (size_t)(h * 128) * K + 64, K, &Bs[1][h][0], t, w);
  if (BH == 2) asm volatile("s_waitcnt vmcnt(4)" ::: "memory");
  else         asm volatile("s_waitcnt vmcnt(2)" ::: "memory");
  __builtin_amdgcn_s_barrier();

  f32x4 acc[MI][4] = {};
  bf16x8 bfr[4][2];

  for (int kt = 0; kt < NT; ++kt) {
    const int d = kt & 1;
    const __bf16* An = Ab + (size_t)(kt + 1) * 64;  // A(t+1)
    const __bf16* Bn = Bb + (size_t)(kt + 2) * 64;  // B(t+2)
#pragma unroll
    for (int q = 0; q < 4; ++q) {
      // ---- ds reads (conflict-free: 256B contiguous per quarter-wave) ----
      bf16x8 af[MIP][2];
#pragma unroll
      for (int m2 = 0; m2 < MIP; ++m2)
#pragma unroll
        for (int kk = 0; kk < 2; ++kk)
          af[m2][kk] = *(const bf16x8*)
              &As[d][ah][((kk * 4 + kb) * 128 + ar0 + (q * MIP + m2) * 16 + lm) * 8];
      if (q == 0) {
#pragma unroll
        for (int ni = 0; ni < 4; ++ni)
#pragma unroll
          for (int kk = 0; kk < 2; ++kk)
            bfr[ni][kk] = *(const bf16x8*)
                &Bs[d][bh][((kk * 4 + kb) * 128 + bc0 + ni * 16 + lm) * 8];
      }
      // ---- stage issues (A(t+1) -> dbuf d^1; B(t+2) -> dbuf d) ----
      if (q == 0 && kt + 1 < NT)
        stage_half(An, K, &As[d ^ 1][0][0], t, w);
      if (q == 1) {
        if (kt + 1 < NT) stage_half(An + (size_t)128 * K, K, &As[d ^ 1][1][0], t, w);
        if (BH == 2 && kt + 2 < NT) stage_half(Bn, K, &Bs[d][0][0], t, w);
      }
      if (q == 2 && kt + 2 < NT)
        stage_half(Bn + (size_t)((BH - 1) * 128) * K, K, &Bs[d][BH - 1][0], t, w);

      __builtin_amdgcn_s_barrier();
      __builtin_amdgcn_s_setprio(1);
#pragma unroll
      for (int m2 = 0; m2 < MIP; ++m2)
#pragma unroll
        for (int ni = 0; ni < 4; ++ni)
#pragma unroll
          for (int kk = 0; kk < 2; ++kk)
            acc[q * MIP + m2][ni] = __builtin_amdgcn_mfma_f32_16x16x32_bf16(
                af[m2][kk], bfr[ni][kk], acc[q * MIP + m2][ni], 0, 0, 0);
      __builtin_amdgcn_s_setprio(0);
      if (q == 3) {
        if (kt < NT - 2) {
          // steady state: allow only B(t+2)'s loads to remain outstanding
          if (BH == 2) asm volatile("s_waitcnt vmcnt(4)" ::: "memory");
          else         asm volatile("s_waitcnt vmcnt(2)" ::: "memory");
        } else if (kt == NT - 2) {
          asm volatile("s_waitcnt vmcnt(0)" ::: "memory");  // drain for last tile
        }
      }
      __builtin_amdgcn_s_barrier();
    }
  }

  // ---- epilogue ----
#pragma unroll
  for (int mi = 0; mi < MI; ++mi) {
#pragma unroll
    for (int ni = 0; ni < 4; ++ni) {
      const int col = bn0 + wn * 64 + ni * 16 + lm;
#pragma unroll
      for (int r = 0; r < 4; ++r) {
        const int row = bm0 + wm * WR + mi * 16 + kb * 4 + r;
        const size_t idx = (size_t)row * N + col;
        if (EPI == 0)
          ((__bf16*)Cv)[idx] = (__bf16)acc[mi][ni][r];
        else
          ((float*)Cv)[idx] = addend[idx] + acc[mi][ni][r];
      }
    }
  }
}

// ---------------- silu(gate) * up ----------------
__global__ __launch_bounds__(256) void silu_mul_kernel(
    const __bf16* __restrict__ gu, __bf16* __restrict__ act) {
  const size_t tid = (size_t)blockIdx.x * 256 + threadIdx.x;
  const size_t row = tid >> 10;
  const size_t c8 = (tid & 1023) * 8;
  const bf16x8 g = *(const bf16x8*)&gu[row * 16384 + c8];
  const bf16x8 u = *(const bf16x8*)&gu[row * 16384 + 8192 + c8];
  bf16x8 o;
#pragma unroll
  for (int j = 0; j < 8; j++) {
    float gf = (float)g[j], uf = (float)u[j];
    o[j] = (__bf16)(uf * (gf / (1.0f + __expf(-gf))));
  }
  *(bf16x8*)&act[row * 8192 + c8] = o;
}

extern "C" void kernel_launch(void* const* d_in, const int* in_sizes, int n_in,
                              void* d_out, int out_size, void* d_ws, size_t ws_size,
                              hipStream_t stream) {
  const float* x      = (const float*)d_in[0];
  const float* ln1    = (const float*)d_in[1];
  const float* ln2    = (const float*)d_in[2];
  const int*   qkv_qw = (const int*)d_in[3];
  const int*   qkv_qz = (const int*)d_in[4];
  const float* qkv_sc = (const float*)d_in[5];
  const int*   o_qw   = (const int*)d_in[6];
  const int*   o_qz   = (const int*)d_in[7];
  const float* o_sc   = (const float*)d_in[8];
  const int*   gu_qw  = (const int*)d_in[9];
  const int*   gu_qz  = (const int*)d_in[10];
  const float* gu_sc  = (const float*)d_in[11];
  const int*   dn_qw  = (const int*)d_in[12];
  const int*   dn_qz  = (const int*)d_in[13];
  const float* dn_sc  = (const float*)d_in[14];

  constexpr int H = 2048, I = 8192, M = 4096;

  // Workspace layout (with region reuse):
  char* ws = (char*)d_ws;
  __bf16* h   = (__bf16*)(ws + 0);                 // 16 MiB
  __bf16* q   = (__bf16*)(ws + 16777216ULL);       // 16 MiB
  float*  x2  = (float*)(ws + 33554432ULL);        // 32 MiB
  __bf16* W   = (__bf16*)(ws + 67108864ULL);       // 64 MiB weight^T (reused)
  __bf16* act = W;                                 // [4096][8192] bf16 (Wgu dead)
  __bf16* gu  = (__bf16*)(ws + 134217728ULL);      // 128 MiB
  __bf16* Wdn = (__bf16*)(ws + 0);                 // 32 MiB (h,q dead)

  // 1. h1 = rmsnorm(x, ln1)
  rmsnorm_kernel<<<dim3(M), dim3(256), 0, stream>>>(x, ln1, h);
  // 2. Wq^T (only first 2048 cols of qkv used by reference)
  dequant_t_kernel<<<dim3(H / 64, 4), dim3(256), 0, stream>>>(qkv_qw, qkv_qz, qkv_sc, W, H, 768, 6144);
  // 3. q = h1 @ Wq
  gemm8p_kernel<128, 0><<<dim3((M / 256) * (H / 128)), dim3(512), 0, stream>>>(h, W, (void*)q, nullptr, M, H, H);
  // 4. Wo^T
  dequant_t_kernel<<<dim3(H / 64, 4), dim3(256), 0, stream>>>(o_qw, o_qz, o_sc, W, H, 256, 2048);
  // 5. x2 = x + q @ Wo
  gemm8p_kernel<128, 1><<<dim3((M / 256) * (H / 128)), dim3(512), 0, stream>>>(q, W, (void*)x2, x, M, H, H);
  // 6. h2 = rmsnorm(x2, ln2)
  rmsnorm_kernel<<<dim3(M), dim3(256), 0, stream>>>(x2, ln2, h);
  // 7. Wgu^T [16384][2048]
  dequant_t_kernel<<<dim3(H / 64, 32), dim3(256), 0, stream>>>(gu_qw, gu_qz, gu_sc, W, H, 2048, 16384);
  // 8. gate_up = h2 @ Wgu
  gemm8p_kernel<256, 0><<<dim3((M / 256) * (2 * I / 256)), dim3(512), 0, stream>>>(h, W, (void*)gu, nullptr, M, 2 * I, H);
  // 9. act = silu(gate) * up
  silu_mul_kernel<<<dim3(M * (I / 8) / 256), dim3(256), 0, stream>>>(gu, act);
  // 10. Wdn^T [2048][8192]
  dequant_t_kernel<<<dim3(I / 64, 4), dim3(256), 0, stream>>>(dn_qw, dn_qz, dn_sc, Wdn, I, 256, 2048);
  // 11. out = x2 + act @ Wdn
  gemm8p_kernel<128, 1><<<dim3((M / 256) * (H / 128)), dim3(512), 0, stream>>>(act, Wdn, d_out, x2, M, H, I);
}